// Round 21
// baseline (823.349 us; speedup 1.0000x reference)
//
#include <hip/hip_runtime.h>
#include <math.h>

#define BB 8
#define IMGS 224
#define PSZ 16
#define CC 96
#define DEPTH 12
#define NCLS 43
#define HH 14
#define WW 14
#define LL 196
#define DD 192
#define NSTATE 16
#define RRANK 6
#define KDIR 4
#define DBLC 38     // R + 2N = 6 + 32 (logical outputs of x_proj)
#define NSEG 16     // segments per chain
#define PTOK 4      // tokens per patch-embed block
// per-(b,k) dbl region: dtT[6][200] + B[196][16] + Ct[16][200]
#define TSTR 200    // row stride for dtT / Ct
#define OFF_B 1200
#define OFF_C 4336
#define DBKSZ 7552  // 1200 + 3136 + 3200 + 16 pad
#define XT 14       // tokens per x_proj tile (14 tiles -> 448 blocks)
#define XPAD 196    // x-tile row stride (mult of 4 => float4-aligned LDS reads)
#define GT 4        // tokens per gateproj block (392 blocks); 4 | 196 so same b, consecutive l
#define YSTRIDE (BB * DD * LL)  // per-direction ysum plane

__device__ __forceinline__ float wave_sum(float v) {
#pragma unroll
  for (int m = 32; m; m >>= 1) v += __shfl_xor(v, m, 64);
  return v;
}

__device__ __forceinline__ float silu_f(float x) {
  return x / (1.f + __expf(-x));
}

// ---------------- patch embed: 4 tokens/block, LDS-staged patch, contiguous weight reads ----------------
__global__ void k_patch(const float* __restrict__ x, const float* __restrict__ pw,
                        const float* __restrict__ pb, const float* __restrict__ pos,
                        float* __restrict__ t) {
  __shared__ float s_x[PTOK][768];  // 3*16*16 per token
  int tok0 = blockIdx.x * PTOK;
  for (int tk = 0; tk < PTOK; tk++) {
    int tok = tok0 + tk;
    int b = tok / LL, l = tok % LL;
    int ph = l / WW, pwc = l % WW;
    for (int e = threadIdx.x; e < 768; e += 128) {
      int ci = e >> 8, kh = (e >> 4) & 15, kw = e & 15;
      s_x[tk][e] = x[((size_t)(b * 3 + ci) * IMGS + ph * PSZ + kh) * IMGS + pwc * PSZ + kw];
    }
  }
  __syncthreads();
  if (threadIdx.x < CC) {
    int c = threadIdx.x;
    float a0 = pb[c], a1 = a0, a2 = a0, a3 = a0;
    const float* wr = pw + (size_t)c * 768;
    for (int e = 0; e < 768; e++) {
      float wv = wr[e];
      a0 += s_x[0][e] * wv;
      a1 += s_x[1][e] * wv;
      a2 += s_x[2][e] * wv;
      a3 += s_x[3][e] * wv;
    }
    float acc[4] = {a0, a1, a2, a3};
    for (int tk = 0; tk < PTOK; tk++) {
      int tok = tok0 + tk;
      t[(size_t)tok * CC + c] = acc[tk] + pos[(tok % LL) * CC + c];
    }
  }
}

// ---------------- fused LN(96) + in_proj -> xa,z (B,L,D each); layer 0 only ----------------
__global__ void k_lnproj(const float* __restrict__ t, const float* __restrict__ w,
                         const float* __restrict__ bias, const float* __restrict__ ipw,
                         float* __restrict__ xa, float* __restrict__ z) {
  __shared__ float s_x[CC];
  int tok = blockIdx.x;
  int tid = threadIdx.x;
  if (tid < 64) {
    int lane = tid;
    const float* p = t + (size_t)tok * CC;
    float v0 = p[lane];
    float v1 = (lane < CC - 64) ? p[lane + 64] : 0.f;
    float mu = wave_sum(v0 + v1) * (1.f / CC);
    float d0 = v0 - mu;
    float d1 = (lane < CC - 64) ? (v1 - mu) : 0.f;
    float var = wave_sum(d0 * d0 + d1 * d1) * (1.f / CC);
    float rs = rsqrtf(var + 1e-6f);
    s_x[lane] = d0 * rs * w[lane] + bias[lane];
    if (lane < CC - 64) s_x[lane + 64] = d1 * rs * w[lane + 64] + bias[lane + 64];
  }
  __syncthreads();
  int j = tid;  // 0..383
  float acc = 0.f;
  for (int c = 0; c < CC; c++) acc += s_x[c] * ipw[(size_t)c * (2 * DD) + j];
  if (j < DD) xa[(size_t)tok * DD + j] = acc;
  else z[(size_t)tok * DD + (j - DD)] = acc;
}

// ---------------- depthwise 3x3 + bias + SiLU -> xcT (B,L,D); float4 + interior fast path ----------------
__global__ void k_conv(const float* __restrict__ xa, const float* __restrict__ cw,
                       const float* __restrict__ cb, float* __restrict__ xcT) {
  int idx = blockIdx.x * blockDim.x + threadIdx.x;
  if (idx >= BB * LL * (DD / 4)) return;
  int d4 = idx % (DD / 4);
  int d = d4 * 4;
  int rem = idx / (DD / 4);
  int l = rem % LL;
  int b = rem / LL;
  int h = l / WW, w = l % WW;
  float a0 = cb[d], a1 = cb[d + 1], a2 = cb[d + 2], a3 = cb[d + 3];
  if (h >= 1 && h < HH - 1 && w >= 1 && w < WW - 1) {
    // interior: no boundary checks
#pragma unroll
    for (int kh = 0; kh < 3; kh++) {
#pragma unroll
      for (int kw = 0; kw < 3; kw++) {
        const float4 v = *(const float4*)(
            xa + ((size_t)(b * LL + (h + kh - 1) * WW + (w + kw - 1))) * DD + d);
        int wo = kh * 3 + kw;
        a0 += v.x * cw[(d + 0) * 9 + wo];
        a1 += v.y * cw[(d + 1) * 9 + wo];
        a2 += v.z * cw[(d + 2) * 9 + wo];
        a3 += v.w * cw[(d + 3) * 9 + wo];
      }
    }
  } else {
    for (int kh = 0; kh < 3; kh++) {
      int hh = h + kh - 1;
      if (hh < 0 || hh >= HH) continue;
      for (int kw = 0; kw < 3; kw++) {
        int ww = w + kw - 1;
        if (ww < 0 || ww >= WW) continue;
        const float4 v = *(const float4*)(xa + ((size_t)(b * LL + hh * WW + ww)) * DD + d);
        int wo = kh * 3 + kw;
        a0 += v.x * cw[(d + 0) * 9 + wo];
        a1 += v.y * cw[(d + 1) * 9 + wo];
        a2 += v.z * cw[(d + 2) * 9 + wo];
        a3 += v.w * cw[(d + 3) * 9 + wo];
      }
    }
  }
  float4 r = make_float4(silu_f(a0), silu_f(a1), silu_f(a2), silu_f(a3));
  *(float4*)(xcT + ((size_t)(b * LL) + l) * DD + d) = r;
}

// ---------------- x_proj v6: multi-c register reuse (x float4 loaded once per 3 c's) ----------------
__global__ __launch_bounds__(256, 4) void k_xproj(
    const float* __restrict__ xcT, const float* __restrict__ xpw,
    float* __restrict__ dbl) {
  __shared__ float s_w[DBLC * DD];    // 38 x 192 = 29184 B
  __shared__ float s_x[XT * XPAD];    // 14 x 196 = 10976 B  (total 40160 B, 4 blocks/CU)
  int lt = blockIdx.x;  // 0..13
  int k = blockIdx.y;
  int b = blockIdx.z;
  int tid = threadIdx.x;
  int l0 = lt * XT;

  const float* wsrc = xpw + (size_t)k * DBLC * DD;
  for (int idx = tid; idx < DBLC * DD; idx += 256) s_w[idx] = wsrc[idx];
  for (int idx = tid; idx < XT * DD; idx += 256) {
    int i = idx / DD, d = idx % DD;
    int l = l0 + i;
    int lr = (k >= 2) ? (LL - 1 - l) : l;
    int src = (k & 1) ? ((lr % HH) * WW + lr / HH) : lr;
    s_x[i * XPAD + d] = xcT[((size_t)b * LL + src) * DD + d];
  }
  __syncthreads();

  int li = tid & 15;        // token within tile (14 used, 2 idle)
  int cb = tid >> 4;        // 0..15 -> this thread owns c = cb, cb+16, (cb+32 if cb<6)
  if (li >= XT) return;
  int l = l0 + li;
  float* base = dbl + (size_t)(b * KDIR + k) * DBKSZ;
  const float4* xr = (const float4*)(s_x + li * XPAD);
  const float4* w0 = (const float4*)(s_w + cb * DD);
  const float4* w1 = (const float4*)(s_w + (cb + 16) * DD);
  bool has2 = (cb < DBLC - 32);  // cb < 6
  const float4* w2 = has2 ? (const float4*)(s_w + (cb + 32) * DD) : w0;
  float a0 = 0.f, a1 = 0.f, a2 = 0.f;
#pragma unroll 8
  for (int q = 0; q < DD / 4; q++) {
    float4 a = xr[q];  // x loaded ONCE, reused for all 3 c's
    float4 v0 = w0[q], v1 = w1[q], v2 = w2[q];
    a0 += a.x * v0.x + a.y * v0.y + a.z * v0.z + a.w * v0.w;
    a1 += a.x * v1.x + a.y * v1.y + a.z * v1.z + a.w * v1.w;
    a2 += a.x * v2.x + a.y * v2.y + a.z * v2.z + a.w * v2.w;
  }
  // c = cb: dt (cb<6) or B (6..15)
  {
    int c = cb;
    if (c < RRANK) base[c * TSTR + l] = a0;
    else base[OFF_B + l * NSTATE + (c - RRANK)] = a0;
  }
  // c = cb+16: B (16..21) or C (22..31)
  {
    int c = cb + 16;
    if (c < RRANK + NSTATE) base[OFF_B + l * NSTATE + (c - RRANK)] = a1;
    else base[OFF_C + (c - RRANK - NSTATE) * TSTR + l] = a1;
  }
  // c = cb+32: C (32..37), only cb<6
  if (has2) {
    int c = cb + 32;
    base[OFF_C + (c - RRANK - NSTATE) * TSTR + l] = a2;
  }
}

// ---------------- selective scan v10: one block per (b,d,k); coalesced (B,D,L) store ----------------
__global__ __launch_bounds__(256, 8) void k_scan(
    const float* __restrict__ xcT, const float* __restrict__ dbl,
    const float* __restrict__ dtw, const float* __restrict__ dtb,
    const float* __restrict__ alog, const float* __restrict__ dsv,
    float* __restrict__ ysum) {
  __shared__ float s_h[NSTATE][LL + 1];  // stride 197: conflict-free (gcd(5,32)=1)
  __shared__ float s_dt[LL];
  __shared__ float s_u[LL];
  __shared__ float s_xv[LL];
  __shared__ float s_cumdt[LL];
  __shared__ unsigned short s_src[LL];
  __shared__ float s_hin[NSEG][NSTATE];
  __shared__ float s_hend[NSEG][NSTATE];
  __shared__ float s_cum[NSEG][NSTATE];
  __shared__ float s_segsum[NSEG];
  __shared__ float s_A[NSTATE];
  __shared__ float s_y[LL];
  int tid = threadIdx.x;
  int s = tid >> 4;   // segment 0..15
  int n = tid & 15;   // state
  int bd = blockIdx.x;
  int d = bd % DD;
  int b = bd / DD;
  int k = blockIdx.y;  // direction 0..3

  // segment extents: first 4 have 13 steps, rest 12 (4*13 + 12*12 = 196)
  int len = (s < 4) ? 13 : 12;
  int l0 = s * 12 + ((s < 4) ? s : 4);
  const float* xcb = xcT + (size_t)b * LL * DD + d;

  float A = -__expf(alog[((size_t)k * DD + d) * NSTATE + n]);
  float Dsc = dsv[k * DD + d];
  const float* blp = dbl + (size_t)(b * KDIR + k) * DBKSZ;
  if (tid < NSTATE) s_A[tid] = A;

  // ---- phase 0: parallel per-token precompute ----
  if (tid < LL) {
    const float* wp = dtw + ((size_t)k * DD + d) * RRANK;
    int l = tid;
    float m = dtb[k * DD + d];
#pragma unroll
    for (int r = 0; r < RRANK; r++) m += blp[r * TSTR + l] * wp[r];
    float dtl = (m > 20.f) ? m : __logf(1.f + __expf(m));
    int lr = (k >= 2) ? (LL - 1 - l) : l;
    int src = (k & 1) ? ((lr % HH) * WW + lr / HH) : lr;
    float xv = xcb[(size_t)src * DD];
    s_dt[l] = dtl;
    s_src[l] = (unsigned short)src;
    s_xv[l] = xv;
    s_u[l] = dtl * xv;
  }
  __syncthreads();

  // per-token inclusive prefix sum of dt within its segment
  if (tid < LL) {
    int l = tid;
    int myseg = (l < 52) ? (l / 13) : (4 + (l - 52) / 12);
    int sl0 = myseg * 12 + ((myseg < 4) ? myseg : 4);
    float acc = 0.f;
    for (int j = sl0; j <= l; j++) acc += s_dt[j];
    s_cumdt[l] = acc;
    int slen = (myseg < 4) ? 13 : 12;
    if (l == sl0 + slen - 1) s_segsum[myseg] = acc;
  }
  __syncthreads();

  // ---- pass 1: serial local scan from h=0 (B prefetched); cum via parallel exp ----
  float Breg[13];
#pragma unroll
  for (int i = 0; i < 13; i++) {
    int li = (i < len) ? (l0 + i) : l0;
    Breg[i] = blp[OFF_B + li * NSTATE + n];
  }
  float h = 0.f;
#pragma unroll
  for (int i = 0; i < 13; i++) {
    if (i < len) {
      int l = l0 + i;
      float a = __expf(s_dt[l] * A);
      h = h * a + s_u[l] * Breg[i];
      s_h[n][l] = h;
    }
  }
  s_hend[s][n] = h;
  s_cum[s][n] = __expf(A * s_segsum[s]);
  __syncthreads();

  // ---- combine: each (s,n) thread computes its own h_in (<=15 FMA chain) ----
  {
    float hh = 0.f;
    for (int ss = 0; ss < s; ss++) hh = s_cum[ss][n] * hh + s_hend[ss][n];
    s_hin[s][n] = hh;
  }
  __syncthreads();

  // ---- phase 2: fully parallel y per token; stage through s_y for coalesced store ----
  if (tid < LL) {
    int l = tid;
    int myseg = (l < 52) ? (l / 13) : (4 + (l - 52) / 12);
    float cd = s_cumdt[l];
    const float* q = blp + OFF_C + l;  // Ct[nn][l], stride TSTR
    float y = 0.f;
#pragma unroll
    for (int nn = 0; nn < NSTATE; nn++) {
      float hf = s_h[nn][l] + __expf(s_A[nn] * cd) * s_hin[myseg][nn];
      y += hf * q[nn * TSTR];
    }
    y += Dsc * s_xv[l];
    s_y[s_src[l]] = y;
  }
  __syncthreads();
  if (tid < LL)
    ysum[(size_t)k * YSTRIDE + ((size_t)b * DD + d) * LL + tid] = s_y[tid];
}

// ---- fused gate+proj v4: 4 tokens/block; float4 row reads of ysum; mode-switched tail ----
// mode 1: out_proj + residual + next-layer LN(96)+in_proj -> xa,zout
// mode 2: out_proj + residual + FINAL LN * (1/L) -> t2 (passed via xa)
__global__ void k_gateproj(const float* __restrict__ ys,
                           const float* __restrict__ onw, const float* __restrict__ onb,
                           const float* __restrict__ z, const float* __restrict__ opw,
                           float* __restrict__ t,
                           const float* __restrict__ nlw, const float* __restrict__ nlb,
                           const float* __restrict__ ipw,
                           float* __restrict__ xa, float* __restrict__ zout, int mode) {
  __shared__ float s_g[GT][DD];
  __shared__ float s_r2[2][3];
  __shared__ float s_t[GT][CC];
  __shared__ float s_x[GT][CC];
  __shared__ float s_p[4][GT][CC];
  int tok0 = blockIdx.x * GT;
  int b = tok0 / LL;   // GT | LL so all 4 tokens share b
  int l0 = tok0 % LL;  // consecutive l0..l0+3
  int tid = threadIdx.x;

  // stage 1a: per-d float4 row loads (4 tokens at once), sum 4 direction planes, transpose
  if (tid < DD) {
    size_t base = ((size_t)b * DD + tid) * LL + l0;
    float4 v0 = *(const float4*)(ys + base);
    float4 v1 = *(const float4*)(ys + (size_t)YSTRIDE + base);
    float4 v2 = *(const float4*)(ys + 2 * (size_t)YSTRIDE + base);
    float4 v3 = *(const float4*)(ys + 3 * (size_t)YSTRIDE + base);
    s_g[0][tid] = v0.x + v1.x + v2.x + v3.x;
    s_g[1][tid] = v0.y + v1.y + v2.y + v3.y;
    s_g[2][tid] = v0.z + v1.z + v2.z + v3.z;
    s_g[3][tid] = v0.w + v1.w + v2.w + v3.w;
  }
  __syncthreads();

  // stage 1b: LN(192)+silu-gate from LDS, 2 tokens at a time
  int sub = tid / 192;       // 0/1
  int dd = tid % 192;
  int wvin = (tid % 192) / 64;
#pragma unroll
  for (int pass = 0; pass < GT / 2; pass++) {
    int tk = pass * 2 + sub;
    int tok = tok0 + tk;
    float v = s_g[tk][dd];
    float p1 = wave_sum(v);
    if ((tid & 63) == 0) s_r2[sub][wvin] = p1;
    __syncthreads();
    float mu = (s_r2[sub][0] + s_r2[sub][1] + s_r2[sub][2]) * (1.f / DD);
    __syncthreads();
    float dv = v - mu;
    float p2 = wave_sum(dv * dv);
    if ((tid & 63) == 0) s_r2[sub][wvin] = p2;
    __syncthreads();
    float var = (s_r2[sub][0] + s_r2[sub][1] + s_r2[sub][2]) * (1.f / DD);
    float rs = rsqrtf(var + 1e-6f);
    float zz = z[(size_t)tok * DD + dd];
    s_g[tk][dd] = (dv * rs * onw[dd] + onb[dd]) * silu_f(zz);
    __syncthreads();
  }

  // stage 2: out_proj partials, weights read once for 4 tokens
  {
    int c = tid % CC;
    int part = tid / CC;  // 0..3
    int dlo = part * 48;
    float a0 = 0.f, a1 = 0.f, a2 = 0.f, a3 = 0.f;
#pragma unroll 8
    for (int j = 0; j < 48; j++) {
      float wv = opw[(size_t)(dlo + j) * CC + c];
      a0 += s_g[0][dlo + j] * wv;
      a1 += s_g[1][dlo + j] * wv;
      a2 += s_g[2][dlo + j] * wv;
      a3 += s_g[3][dlo + j] * wv;
    }
    s_p[part][0][c] = a0;
    s_p[part][1][c] = a1;
    s_p[part][2][c] = a2;
    s_p[part][3][c] = a3;
  }
  __syncthreads();
  // residual + t update
  {
    int tk = tid / CC;  // 0..3
    int c = tid % CC;
    float tn = t[(size_t)(tok0 + tk) * CC + c] +
               s_p[0][tk][c] + s_p[1][tk][c] + s_p[2][tk][c] + s_p[3][tk][c];
    t[(size_t)(tok0 + tk) * CC + c] = tn;
    s_t[tk][c] = tn;
  }
  __syncthreads();

  // stage 3: LN(96) with nlw/nlb (next layer's ln1, or final norm in mode 2)
  {
    int w = tid >> 6;   // 0..5
    int lane = tid & 63;
    if (w < GT) {
      float v0 = s_t[w][lane];
      float v1 = (lane < CC - 64) ? s_t[w][lane + 64] : 0.f;
      float mu2 = wave_sum(v0 + v1) * (1.f / CC);
      float d0 = v0 - mu2;
      float d1 = (lane < CC - 64) ? (v1 - mu2) : 0.f;
      float var2 = wave_sum(d0 * d0 + d1 * d1) * (1.f / CC);
      float rs2 = rsqrtf(var2 + 1e-6f);
      s_x[w][lane] = d0 * rs2 * nlw[lane] + nlb[lane];
      if (lane < CC - 64) s_x[w][lane + 64] = d1 * rs2 * nlw[lane + 64] + nlb[lane + 64];
    }
  }
  __syncthreads();

  if (mode == 2) {
    // final: t2 = LN_final(t) * (1/L)   (t2 passed via xa)
    int tk = tid / CC;  // 0..3
    int c = tid % CC;
    xa[(size_t)(tok0 + tk) * CC + c] = s_x[tk][c] * (1.f / LL);
    return;
  }

  // stage 4: next layer's in_proj, weights read once for 4 tokens
  {
    float b0 = 0.f, b1 = 0.f, b2 = 0.f, b3 = 0.f;
    for (int c = 0; c < CC; c++) {
      float wv = ipw[(size_t)c * (2 * DD) + tid];
      b0 += s_x[0][c] * wv;
      b1 += s_x[1][c] * wv;
      b2 += s_x[2][c] * wv;
      b3 += s_x[3][c] * wv;
    }
    float acc[GT] = {b0, b1, b2, b3};
#pragma unroll
    for (int tk = 0; tk < GT; tk++) {
      int tok = tok0 + tk;
      if (tid < DD) xa[(size_t)tok * DD + tid] = acc[tk];
      else zout[(size_t)tok * DD + (tid - DD)] = acc[tk];
    }
  }
}

// ---------------- pooled head: 8 blocks x 256 thr; 2-way parallel pool + 96x43 matmul ----------------
__global__ void k_head(const float* __restrict__ t2, const float* __restrict__ hw,
                       const float* __restrict__ hb, float* __restrict__ out) {
  __shared__ float s_part[2][CC];
  __shared__ float s_pool[CC];
  int b = blockIdx.x;
  int tid = threadIdx.x;
  if (tid < 2 * CC) {
    int part = tid / CC;  // 0/1
    int c = tid % CC;
    int l0 = part * 98;
    float acc = 0.f;
    for (int i = 0; i < 98; i++) acc += t2[((size_t)b * LL + l0 + i) * CC + c];
    s_part[part][c] = acc;
  }
  __syncthreads();
  if (tid < CC) s_pool[tid] = s_part[0][tid] + s_part[1][tid];
  __syncthreads();
  if (tid < NCLS) {
    float acc = hb[tid];
    for (int c = 0; c < CC; c++) acc += s_pool[c] * hw[c * NCLS + tid];
    out[b * NCLS + tid] = acc;
  }
}

extern "C" void kernel_launch(void* const* d_in, const int* in_sizes, int n_in,
                              void* d_out, int out_size, void* d_ws, size_t ws_size,
                              hipStream_t stream) {
  const float* x       = (const float*)d_in[0];
  const float* patch_w = (const float*)d_in[1];
  const float* patch_b = (const float*)d_in[2];
  const float* pos     = (const float*)d_in[3];
  const float* ln1_w   = (const float*)d_in[4];
  const float* ln1_b   = (const float*)d_in[5];
  const float* ipw     = (const float*)d_in[6];
  const float* cw      = (const float*)d_in[7];
  const float* cb      = (const float*)d_in[8];
  const float* xpw     = (const float*)d_in[9];
  const float* dtw     = (const float*)d_in[10];
  const float* dtb     = (const float*)d_in[11];
  const float* alog    = (const float*)d_in[12];
  const float* dsp     = (const float*)d_in[13];
  const float* onw     = (const float*)d_in[14];
  const float* onb     = (const float*)d_in[15];
  const float* opw     = (const float*)d_in[16];
  const float* nw      = (const float*)d_in[17];
  const float* nb      = (const float*)d_in[18];
  const float* hw      = (const float*)d_in[19];
  const float* hb      = (const float*)d_in[20];
  float* out = (float*)d_out;

  // Workspace (all separate; ws_size = 256 MiB):
  // t + xa + z + xcT + dbl + ysum(4 planes) + t2 = ~10 MB
  float* wsf  = (float*)d_ws;
  float* t    = wsf;
  float* xa   = t    + BB * LL * CC;
  float* z    = xa   + BB * LL * DD;
  float* xcT  = z    + BB * LL * DD;
  float* dbl  = xcT  + BB * LL * DD;
  float* ysum = dbl  + BB * KDIR * DBKSZ;
  float* t2   = ysum + (size_t)KDIR * YSTRIDE;

  k_patch<<<BB * LL / PTOK, 128, 0, stream>>>(x, patch_w, patch_b, pos, t);
  k_lnproj<<<BB * LL, 384, 0, stream>>>(t, ln1_w, ln1_b, ipw, xa, z);

  for (int i = 0; i < DEPTH; i++) {
    k_conv<<<(BB * LL * (DD / 4) + 255) / 256, 256, 0, stream>>>(
        xa, cw + i * DD * 9, cb + i * DD, xcT);
    k_xproj<<<dim3(LL / XT, KDIR, BB), 256, 0, stream>>>(
        xcT, xpw + (size_t)i * KDIR * DBLC * DD, dbl);
    // one block per (b,d,k): 1536 x 4 blocks
    k_scan<<<dim3(BB * DD, KDIR), 256, 0, stream>>>(
        xcT, dbl, dtw + (size_t)i * KDIR * DD * RRANK, dtb + i * KDIR * DD,
        alog + (size_t)i * KDIR * DD * NSTATE, dsp + i * KDIR * DD, ysum);
    if (i < DEPTH - 1) {
      k_gateproj<<<BB * LL / GT, 384, 0, stream>>>(
          ysum, onw + i * DD, onb + i * DD, z, opw + (size_t)i * DD * CC, t,
          ln1_w + (i + 1) * CC, ln1_b + (i + 1) * CC, ipw + (size_t)(i + 1) * CC * 2 * DD,
          xa, z, 1);
    } else {
      // mode 2: fold final LN + 1/L into the last gateproj; t2 via xa slot
      k_gateproj<<<BB * LL / GT, 384, 0, stream>>>(
          ysum, onw + i * DD, onb + i * DD, z, opw + (size_t)i * DD * CC, t,
          nw, nb, ipw, t2, z, 2);
    }
  }

  k_head<<<BB, 256, 0, stream>>>(t2, hw, hb, out);
}

// Round 22
// 811.024 us; speedup vs baseline: 1.0152x; 1.0152x over previous
//
#include <hip/hip_runtime.h>
#include <math.h>

#define BB 8
#define IMGS 224
#define PSZ 16
#define CC 96
#define DEPTH 12
#define NCLS 43
#define HH 14
#define WW 14
#define LL 196
#define DD 192
#define NSTATE 16
#define RRANK 6
#define KDIR 4
#define DBLC 38     // R + 2N = 6 + 32 (logical outputs of x_proj)
#define NSEG 16     // segments per chain
#define PTOK 4      // tokens per patch-embed block
// per-(b,k) dbl region: dtT[6][200] + B[196][16] + Ct[16][200]
#define TSTR 200    // row stride for dtT / Ct
#define OFF_B 1200
#define OFF_C 4336
#define DBKSZ 7552  // 1200 + 3136 + 3200 + 16 pad
#define XT 14       // tokens per x_proj tile (14 tiles -> 448 blocks)
#define XPAD 196    // x-tile row stride (mult of 4 => float4-aligned LDS reads)
#define GT 4        // tokens per gateproj block (392 blocks); 4 | 196 so same b, consecutive l
#define YSTRIDE (BB * DD * LL)  // per-direction ysum plane

__device__ __forceinline__ float wave_sum(float v) {
#pragma unroll
  for (int m = 32; m; m >>= 1) v += __shfl_xor(v, m, 64);
  return v;
}

__device__ __forceinline__ float silu_f(float x) {
  return x / (1.f + __expf(-x));
}

// ---------------- patch embed: 4 tokens/block, LDS-staged patch, contiguous weight reads ----------------
__global__ void k_patch(const float* __restrict__ x, const float* __restrict__ pw,
                        const float* __restrict__ pb, const float* __restrict__ pos,
                        float* __restrict__ t) {
  __shared__ float s_x[PTOK][768];  // 3*16*16 per token
  int tok0 = blockIdx.x * PTOK;
  for (int tk = 0; tk < PTOK; tk++) {
    int tok = tok0 + tk;
    int b = tok / LL, l = tok % LL;
    int ph = l / WW, pwc = l % WW;
    for (int e = threadIdx.x; e < 768; e += 128) {
      int ci = e >> 8, kh = (e >> 4) & 15, kw = e & 15;
      s_x[tk][e] = x[((size_t)(b * 3 + ci) * IMGS + ph * PSZ + kh) * IMGS + pwc * PSZ + kw];
    }
  }
  __syncthreads();
  if (threadIdx.x < CC) {
    int c = threadIdx.x;
    float a0 = pb[c], a1 = a0, a2 = a0, a3 = a0;
    const float* wr = pw + (size_t)c * 768;
    for (int e = 0; e < 768; e++) {
      float wv = wr[e];
      a0 += s_x[0][e] * wv;
      a1 += s_x[1][e] * wv;
      a2 += s_x[2][e] * wv;
      a3 += s_x[3][e] * wv;
    }
    float acc[4] = {a0, a1, a2, a3};
    for (int tk = 0; tk < PTOK; tk++) {
      int tok = tok0 + tk;
      t[(size_t)tok * CC + c] = acc[tk] + pos[(tok % LL) * CC + c];
    }
  }
}

// ---------------- fused LN(96) + in_proj -> xa,z (B,L,D each); layer 0 only ----------------
__global__ void k_lnproj(const float* __restrict__ t, const float* __restrict__ w,
                         const float* __restrict__ bias, const float* __restrict__ ipw,
                         float* __restrict__ xa, float* __restrict__ z) {
  __shared__ float s_x[CC];
  int tok = blockIdx.x;
  int tid = threadIdx.x;
  if (tid < 64) {
    int lane = tid;
    const float* p = t + (size_t)tok * CC;
    float v0 = p[lane];
    float v1 = (lane < CC - 64) ? p[lane + 64] : 0.f;
    float mu = wave_sum(v0 + v1) * (1.f / CC);
    float d0 = v0 - mu;
    float d1 = (lane < CC - 64) ? (v1 - mu) : 0.f;
    float var = wave_sum(d0 * d0 + d1 * d1) * (1.f / CC);
    float rs = rsqrtf(var + 1e-6f);
    s_x[lane] = d0 * rs * w[lane] + bias[lane];
    if (lane < CC - 64) s_x[lane + 64] = d1 * rs * w[lane + 64] + bias[lane + 64];
  }
  __syncthreads();
  int j = tid;  // 0..383
  float acc = 0.f;
  for (int c = 0; c < CC; c++) acc += s_x[c] * ipw[(size_t)c * (2 * DD) + j];
  if (j < DD) xa[(size_t)tok * DD + j] = acc;
  else z[(size_t)tok * DD + (j - DD)] = acc;
}

// ---------------- depthwise 3x3 + bias + SiLU -> xcT (B,L,D); float4 + interior fast path ----------------
__global__ void k_conv(const float* __restrict__ xa, const float* __restrict__ cw,
                       const float* __restrict__ cb, float* __restrict__ xcT) {
  int idx = blockIdx.x * blockDim.x + threadIdx.x;
  if (idx >= BB * LL * (DD / 4)) return;
  int d4 = idx % (DD / 4);
  int d = d4 * 4;
  int rem = idx / (DD / 4);
  int l = rem % LL;
  int b = rem / LL;
  int h = l / WW, w = l % WW;
  float a0 = cb[d], a1 = cb[d + 1], a2 = cb[d + 2], a3 = cb[d + 3];
  if (h >= 1 && h < HH - 1 && w >= 1 && w < WW - 1) {
#pragma unroll
    for (int kh = 0; kh < 3; kh++) {
#pragma unroll
      for (int kw = 0; kw < 3; kw++) {
        const float4 v = *(const float4*)(
            xa + ((size_t)(b * LL + (h + kh - 1) * WW + (w + kw - 1))) * DD + d);
        int wo = kh * 3 + kw;
        a0 += v.x * cw[(d + 0) * 9 + wo];
        a1 += v.y * cw[(d + 1) * 9 + wo];
        a2 += v.z * cw[(d + 2) * 9 + wo];
        a3 += v.w * cw[(d + 3) * 9 + wo];
      }
    }
  } else {
    for (int kh = 0; kh < 3; kh++) {
      int hh = h + kh - 1;
      if (hh < 0 || hh >= HH) continue;
      for (int kw = 0; kw < 3; kw++) {
        int ww = w + kw - 1;
        if (ww < 0 || ww >= WW) continue;
        const float4 v = *(const float4*)(xa + ((size_t)(b * LL + hh * WW + ww)) * DD + d);
        int wo = kh * 3 + kw;
        a0 += v.x * cw[(d + 0) * 9 + wo];
        a1 += v.y * cw[(d + 1) * 9 + wo];
        a2 += v.z * cw[(d + 2) * 9 + wo];
        a3 += v.w * cw[(d + 3) * 9 + wo];
      }
    }
  }
  float4 r = make_float4(silu_f(a0), silu_f(a1), silu_f(a2), silu_f(a3));
  *(float4*)(xcT + ((size_t)(b * LL) + l) * DD + d) = r;
}

// ---------------- x_proj v6: multi-c register reuse (x float4 loaded once per 3 c's) ----------------
__global__ __launch_bounds__(256, 4) void k_xproj(
    const float* __restrict__ xcT, const float* __restrict__ xpw,
    float* __restrict__ dbl) {
  __shared__ float s_w[DBLC * DD];    // 38 x 192 = 29184 B
  __shared__ float s_x[XT * XPAD];    // 14 x 196 = 10976 B
  int lt = blockIdx.x;  // 0..13
  int k = blockIdx.y;
  int b = blockIdx.z;
  int tid = threadIdx.x;
  int l0 = lt * XT;

  const float* wsrc = xpw + (size_t)k * DBLC * DD;
  for (int idx = tid; idx < DBLC * DD; idx += 256) s_w[idx] = wsrc[idx];
  for (int idx = tid; idx < XT * DD; idx += 256) {
    int i = idx / DD, d = idx % DD;
    int l = l0 + i;
    int lr = (k >= 2) ? (LL - 1 - l) : l;
    int src = (k & 1) ? ((lr % HH) * WW + lr / HH) : lr;
    s_x[i * XPAD + d] = xcT[((size_t)b * LL + src) * DD + d];
  }
  __syncthreads();

  int li = tid & 15;
  int cb = tid >> 4;        // 0..15 -> c = cb, cb+16, (cb+32 if cb<6)
  if (li >= XT) return;
  int l = l0 + li;
  float* base = dbl + (size_t)(b * KDIR + k) * DBKSZ;
  const float4* xr = (const float4*)(s_x + li * XPAD);
  const float4* w0 = (const float4*)(s_w + cb * DD);
  const float4* w1 = (const float4*)(s_w + (cb + 16) * DD);
  bool has2 = (cb < DBLC - 32);
  const float4* w2 = has2 ? (const float4*)(s_w + (cb + 32) * DD) : w0;
  float a0 = 0.f, a1 = 0.f, a2 = 0.f;
#pragma unroll 8
  for (int q = 0; q < DD / 4; q++) {
    float4 a = xr[q];
    float4 v0 = w0[q], v1 = w1[q], v2 = w2[q];
    a0 += a.x * v0.x + a.y * v0.y + a.z * v0.z + a.w * v0.w;
    a1 += a.x * v1.x + a.y * v1.y + a.z * v1.z + a.w * v1.w;
    a2 += a.x * v2.x + a.y * v2.y + a.z * v2.z + a.w * v2.w;
  }
  {
    int c = cb;
    if (c < RRANK) base[c * TSTR + l] = a0;
    else base[OFF_B + l * NSTATE + (c - RRANK)] = a0;
  }
  {
    int c = cb + 16;
    if (c < RRANK + NSTATE) base[OFF_B + l * NSTATE + (c - RRANK)] = a1;
    else base[OFF_C + (c - RRANK - NSTATE) * TSTR + l] = a1;
  }
  if (has2) {
    int c = cb + 32;
    base[OFF_C + (c - RRANK - NSTATE) * TSTR + l] = a2;
  }
}

// ---------------- selective scan v12: one block per (b, d-PAIR, k); B/C/dt-rows loaded once ----------------
// The B, C, and dt-input arrays are per-(b,k,l) — identical across d. A d-pair block halves
// that traffic; the two recurrence chains are independent (pure ILP, same critical path).
__global__ __launch_bounds__(256, 4) void k_scan(
    const float* __restrict__ xcT, const float* __restrict__ dbl,
    const float* __restrict__ dtw, const float* __restrict__ dtb,
    const float* __restrict__ alog, const float* __restrict__ dsv,
    float* __restrict__ ysum) {
  __shared__ float s_h[2][NSTATE][LL + 1];  // 25.2 KB; stride 197 conflict-free
  __shared__ float s_dt[2][LL];
  __shared__ float s_u[2][LL];
  __shared__ float s_xv[2][LL];
  __shared__ float s_cumdt[2][LL];
  __shared__ unsigned short s_src[LL];
  __shared__ float s_hin[2][NSEG][NSTATE];
  __shared__ float s_hend[2][NSEG][NSTATE];
  __shared__ float s_cum[2][NSEG][NSTATE];
  __shared__ float s_segsum[2][NSEG];
  __shared__ float s_A[2][NSTATE];
  __shared__ float s_y[2][LL];
  int tid = threadIdx.x;
  int s = tid >> 4;   // segment 0..15
  int n = tid & 15;   // state
  int bd = blockIdx.x;
  int dp = bd % (DD / 2);
  int d0 = dp * 2;
  int b = bd / (DD / 2);
  int k = blockIdx.y;  // direction 0..3

  // segment extents: first 4 have 13 steps, rest 12 (4*13 + 12*12 = 196)
  int len = (s < 4) ? 13 : 12;
  int l0 = s * 12 + ((s < 4) ? s : 4);

  float A0 = -__expf(alog[((size_t)k * DD + d0) * NSTATE + n]);
  float A1 = -__expf(alog[((size_t)k * DD + d0 + 1) * NSTATE + n]);
  float Dsc0 = dsv[k * DD + d0];
  float Dsc1 = dsv[k * DD + d0 + 1];
  const float* blp = dbl + (size_t)(b * KDIR + k) * DBKSZ;
  if (tid < NSTATE) { s_A[0][tid] = A0; s_A[1][tid] = A1; }

  // ---- phase 0: parallel per-token precompute; dt-rows + xv loaded ONCE for the pair ----
  if (tid < LL) {
    int l = tid;
    float r[RRANK];
#pragma unroll
    for (int rr = 0; rr < RRANK; rr++) r[rr] = blp[rr * TSTR + l];
    const float* wp0 = dtw + ((size_t)k * DD + d0) * RRANK;
    const float* wp1 = wp0 + RRANK;
    float m0 = dtb[k * DD + d0], m1 = dtb[k * DD + d0 + 1];
#pragma unroll
    for (int rr = 0; rr < RRANK; rr++) { m0 += r[rr] * wp0[rr]; m1 += r[rr] * wp1[rr]; }
    float dt0 = (m0 > 20.f) ? m0 : __logf(1.f + __expf(m0));
    float dt1 = (m1 > 20.f) ? m1 : __logf(1.f + __expf(m1));
    int lr = (k >= 2) ? (LL - 1 - l) : l;
    int src = (k & 1) ? ((lr % HH) * WW + lr / HH) : lr;
    float2 xv = *(const float2*)(xcT + ((size_t)b * LL + src) * DD + d0);
    s_dt[0][l] = dt0; s_dt[1][l] = dt1;
    s_u[0][l] = dt0 * xv.x; s_u[1][l] = dt1 * xv.y;
    s_xv[0][l] = xv.x; s_xv[1][l] = xv.y;
    s_src[l] = (unsigned short)src;
  }
  __syncthreads();

  // per-token inclusive prefix sum of dt within its segment (both d's)
  if (tid < LL) {
    int l = tid;
    int myseg = (l < 52) ? (l / 13) : (4 + (l - 52) / 12);
    int sl0 = myseg * 12 + ((myseg < 4) ? myseg : 4);
    float a0 = 0.f, a1 = 0.f;
    for (int j = sl0; j <= l; j++) { a0 += s_dt[0][j]; a1 += s_dt[1][j]; }
    s_cumdt[0][l] = a0; s_cumdt[1][l] = a1;
    int slen = (myseg < 4) ? 13 : 12;
    if (l == sl0 + slen - 1) { s_segsum[0][myseg] = a0; s_segsum[1][myseg] = a1; }
  }
  __syncthreads();

  // ---- pass 1: two independent serial chains; B prefetched ONCE for the pair ----
  float Breg[13];
#pragma unroll
  for (int i = 0; i < 13; i++) {
    int li = (i < len) ? (l0 + i) : l0;
    Breg[i] = blp[OFF_B + li * NSTATE + n];
  }
  float h0 = 0.f, h1 = 0.f;
#pragma unroll
  for (int i = 0; i < 13; i++) {
    if (i < len) {
      int l = l0 + i;
      float a0 = __expf(s_dt[0][l] * A0);
      float a1 = __expf(s_dt[1][l] * A1);
      h0 = h0 * a0 + s_u[0][l] * Breg[i];
      h1 = h1 * a1 + s_u[1][l] * Breg[i];
      s_h[0][n][l] = h0;
      s_h[1][n][l] = h1;
    }
  }
  s_hend[0][s][n] = h0; s_hend[1][s][n] = h1;
  s_cum[0][s][n] = __expf(A0 * s_segsum[0][s]);
  s_cum[1][s][n] = __expf(A1 * s_segsum[1][s]);
  __syncthreads();

  // ---- combine: each (s,n) thread computes h_in for both d's (independent FMA chains) ----
  {
    float hh0 = 0.f, hh1 = 0.f;
    for (int ss = 0; ss < s; ss++) {
      hh0 = s_cum[0][ss][n] * hh0 + s_hend[0][ss][n];
      hh1 = s_cum[1][ss][n] * hh1 + s_hend[1][ss][n];
    }
    s_hin[0][s][n] = hh0; s_hin[1][s][n] = hh1;
  }
  __syncthreads();

  // ---- phase 2: y per token; C loaded ONCE for the pair ----
  if (tid < LL) {
    int l = tid;
    int myseg = (l < 52) ? (l / 13) : (4 + (l - 52) / 12);
    float cd0 = s_cumdt[0][l], cd1 = s_cumdt[1][l];
    const float* q = blp + OFF_C + l;  // Ct[nn][l], stride TSTR
    float y0 = 0.f, y1 = 0.f;
#pragma unroll
    for (int nn = 0; nn < NSTATE; nn++) {
      float Cv = q[nn * TSTR];
      float hf0 = s_h[0][nn][l] + __expf(s_A[0][nn] * cd0) * s_hin[0][myseg][nn];
      float hf1 = s_h[1][nn][l] + __expf(s_A[1][nn] * cd1) * s_hin[1][myseg][nn];
      y0 += hf0 * Cv;
      y1 += hf1 * Cv;
    }
    y0 += Dsc0 * s_xv[0][l];
    y1 += Dsc1 * s_xv[1][l];
    int src = s_src[l];
    s_y[0][src] = y0;
    s_y[1][src] = y1;
  }
  __syncthreads();
  if (tid < LL) {
    size_t base = (size_t)k * YSTRIDE + ((size_t)b * DD + d0) * LL;
    ysum[base + tid] = s_y[0][tid];
    ysum[base + LL + tid] = s_y[1][tid];
  }
}

// ---- fused gate+proj v4: 4 tokens/block; float4 row reads of ysum; mode-switched tail ----
// mode 1: out_proj + residual + next-layer LN(96)+in_proj -> xa,zout
// mode 2: out_proj + residual + FINAL LN * (1/L) -> t2 (passed via xa)
__global__ void k_gateproj(const float* __restrict__ ys,
                           const float* __restrict__ onw, const float* __restrict__ onb,
                           const float* __restrict__ z, const float* __restrict__ opw,
                           float* __restrict__ t,
                           const float* __restrict__ nlw, const float* __restrict__ nlb,
                           const float* __restrict__ ipw,
                           float* __restrict__ xa, float* __restrict__ zout, int mode) {
  __shared__ float s_g[GT][DD];
  __shared__ float s_r2[2][3];
  __shared__ float s_t[GT][CC];
  __shared__ float s_x[GT][CC];
  __shared__ float s_p[4][GT][CC];
  int tok0 = blockIdx.x * GT;
  int b = tok0 / LL;
  int l0 = tok0 % LL;
  int tid = threadIdx.x;

  // stage 1a: per-d float4 row loads (4 tokens at once), sum 4 direction planes, transpose
  if (tid < DD) {
    size_t base = ((size_t)b * DD + tid) * LL + l0;
    float4 v0 = *(const float4*)(ys + base);
    float4 v1 = *(const float4*)(ys + (size_t)YSTRIDE + base);
    float4 v2 = *(const float4*)(ys + 2 * (size_t)YSTRIDE + base);
    float4 v3 = *(const float4*)(ys + 3 * (size_t)YSTRIDE + base);
    s_g[0][tid] = v0.x + v1.x + v2.x + v3.x;
    s_g[1][tid] = v0.y + v1.y + v2.y + v3.y;
    s_g[2][tid] = v0.z + v1.z + v2.z + v3.z;
    s_g[3][tid] = v0.w + v1.w + v2.w + v3.w;
  }
  __syncthreads();

  // stage 1b: LN(192)+silu-gate from LDS, 2 tokens at a time
  int sub = tid / 192;
  int dd = tid % 192;
  int wvin = (tid % 192) / 64;
#pragma unroll
  for (int pass = 0; pass < GT / 2; pass++) {
    int tk = pass * 2 + sub;
    int tok = tok0 + tk;
    float v = s_g[tk][dd];
    float p1 = wave_sum(v);
    if ((tid & 63) == 0) s_r2[sub][wvin] = p1;
    __syncthreads();
    float mu = (s_r2[sub][0] + s_r2[sub][1] + s_r2[sub][2]) * (1.f / DD);
    __syncthreads();
    float dv = v - mu;
    float p2 = wave_sum(dv * dv);
    if ((tid & 63) == 0) s_r2[sub][wvin] = p2;
    __syncthreads();
    float var = (s_r2[sub][0] + s_r2[sub][1] + s_r2[sub][2]) * (1.f / DD);
    float rs = rsqrtf(var + 1e-6f);
    float zz = z[(size_t)tok * DD + dd];
    s_g[tk][dd] = (dv * rs * onw[dd] + onb[dd]) * silu_f(zz);
    __syncthreads();
  }

  // stage 2: out_proj partials, weights read once for 4 tokens
  {
    int c = tid % CC;
    int part = tid / CC;
    int dlo = part * 48;
    float a0 = 0.f, a1 = 0.f, a2 = 0.f, a3 = 0.f;
#pragma unroll 8
    for (int j = 0; j < 48; j++) {
      float wv = opw[(size_t)(dlo + j) * CC + c];
      a0 += s_g[0][dlo + j] * wv;
      a1 += s_g[1][dlo + j] * wv;
      a2 += s_g[2][dlo + j] * wv;
      a3 += s_g[3][dlo + j] * wv;
    }
    s_p[part][0][c] = a0;
    s_p[part][1][c] = a1;
    s_p[part][2][c] = a2;
    s_p[part][3][c] = a3;
  }
  __syncthreads();
  // residual + t update
  {
    int tk = tid / CC;
    int c = tid % CC;
    float tn = t[(size_t)(tok0 + tk) * CC + c] +
               s_p[0][tk][c] + s_p[1][tk][c] + s_p[2][tk][c] + s_p[3][tk][c];
    t[(size_t)(tok0 + tk) * CC + c] = tn;
    s_t[tk][c] = tn;
  }
  __syncthreads();

  // stage 3: LN(96) with nlw/nlb (next layer's ln1, or final norm in mode 2)
  {
    int w = tid >> 6;
    int lane = tid & 63;
    if (w < GT) {
      float v0 = s_t[w][lane];
      float v1 = (lane < CC - 64) ? s_t[w][lane + 64] : 0.f;
      float mu2 = wave_sum(v0 + v1) * (1.f / CC);
      float d0 = v0 - mu2;
      float d1 = (lane < CC - 64) ? (v1 - mu2) : 0.f;
      float var2 = wave_sum(d0 * d0 + d1 * d1) * (1.f / CC);
      float rs2 = rsqrtf(var2 + 1e-6f);
      s_x[w][lane] = d0 * rs2 * nlw[lane] + nlb[lane];
      if (lane < CC - 64) s_x[w][lane + 64] = d1 * rs2 * nlw[lane + 64] + nlb[lane + 64];
    }
  }
  __syncthreads();

  if (mode == 2) {
    int tk = tid / CC;
    int c = tid % CC;
    xa[(size_t)(tok0 + tk) * CC + c] = s_x[tk][c] * (1.f / LL);
    return;
  }

  // stage 4: next layer's in_proj, weights read once for 4 tokens
  {
    float b0 = 0.f, b1 = 0.f, b2 = 0.f, b3 = 0.f;
    for (int c = 0; c < CC; c++) {
      float wv = ipw[(size_t)c * (2 * DD) + tid];
      b0 += s_x[0][c] * wv;
      b1 += s_x[1][c] * wv;
      b2 += s_x[2][c] * wv;
      b3 += s_x[3][c] * wv;
    }
    float acc[GT] = {b0, b1, b2, b3};
#pragma unroll
    for (int tk = 0; tk < GT; tk++) {
      int tok = tok0 + tk;
      if (tid < DD) xa[(size_t)tok * DD + tid] = acc[tk];
      else zout[(size_t)tok * DD + (tid - DD)] = acc[tk];
    }
  }
}

// ---------------- pooled head: 8 blocks x 256 thr; 2-way parallel pool + 96x43 matmul ----------------
__global__ void k_head(const float* __restrict__ t2, const float* __restrict__ hw,
                       const float* __restrict__ hb, float* __restrict__ out) {
  __shared__ float s_part[2][CC];
  __shared__ float s_pool[CC];
  int b = blockIdx.x;
  int tid = threadIdx.x;
  if (tid < 2 * CC) {
    int part = tid / CC;
    int c = tid % CC;
    int l0 = part * 98;
    float acc = 0.f;
    for (int i = 0; i < 98; i++) acc += t2[((size_t)b * LL + l0 + i) * CC + c];
    s_part[part][c] = acc;
  }
  __syncthreads();
  if (tid < CC) s_pool[tid] = s_part[0][tid] + s_part[1][tid];
  __syncthreads();
  if (tid < NCLS) {
    float acc = hb[tid];
    for (int c = 0; c < CC; c++) acc += s_pool[c] * hw[c * NCLS + tid];
    out[b * NCLS + tid] = acc;
  }
}

extern "C" void kernel_launch(void* const* d_in, const int* in_sizes, int n_in,
                              void* d_out, int out_size, void* d_ws, size_t ws_size,
                              hipStream_t stream) {
  const float* x       = (const float*)d_in[0];
  const float* patch_w = (const float*)d_in[1];
  const float* patch_b = (const float*)d_in[2];
  const float* pos     = (const float*)d_in[3];
  const float* ln1_w   = (const float*)d_in[4];
  const float* ln1_b   = (const float*)d_in[5];
  const float* ipw     = (const float*)d_in[6];
  const float* cw      = (const float*)d_in[7];
  const float* cb      = (const float*)d_in[8];
  const float* xpw     = (const float*)d_in[9];
  const float* dtw     = (const float*)d_in[10];
  const float* dtb     = (const float*)d_in[11];
  const float* alog    = (const float*)d_in[12];
  const float* dsp     = (const float*)d_in[13];
  const float* onw     = (const float*)d_in[14];
  const float* onb     = (const float*)d_in[15];
  const float* opw     = (const float*)d_in[16];
  const float* nw      = (const float*)d_in[17];
  const float* nb      = (const float*)d_in[18];
  const float* hw      = (const float*)d_in[19];
  const float* hb      = (const float*)d_in[20];
  float* out = (float*)d_out;

  // Workspace (all separate; ws_size = 256 MiB):
  // t + xa + z + xcT + dbl + ysum(4 planes) + t2 = ~10 MB
  float* wsf  = (float*)d_ws;
  float* t    = wsf;
  float* xa   = t    + BB * LL * CC;
  float* z    = xa   + BB * LL * DD;
  float* xcT  = z    + BB * LL * DD;
  float* dbl  = xcT  + BB * LL * DD;
  float* ysum = dbl  + BB * KDIR * DBKSZ;
  float* t2   = ysum + (size_t)KDIR * YSTRIDE;

  k_patch<<<BB * LL / PTOK, 128, 0, stream>>>(x, patch_w, patch_b, pos, t);
  k_lnproj<<<BB * LL, 384, 0, stream>>>(t, ln1_w, ln1_b, ipw, xa, z);

  for (int i = 0; i < DEPTH; i++) {
    k_conv<<<(BB * LL * (DD / 4) + 255) / 256, 256, 0, stream>>>(
        xa, cw + i * DD * 9, cb + i * DD, xcT);
    k_xproj<<<dim3(LL / XT, KDIR, BB), 256, 0, stream>>>(
        xcT, xpw + (size_t)i * KDIR * DBLC * DD, dbl);
    // one block per (b, d-pair, k): 768 x 4 blocks
    k_scan<<<dim3(BB * DD / 2, KDIR), 256, 0, stream>>>(
        xcT, dbl, dtw + (size_t)i * KDIR * DD * RRANK, dtb + i * KDIR * DD,
        alog + (size_t)i * KDIR * DD * NSTATE, dsp + i * KDIR * DD, ysum);
    if (i < DEPTH - 1) {
      k_gateproj<<<BB * LL / GT, 384, 0, stream>>>(
          ysum, onw + i * DD, onb + i * DD, z, opw + (size_t)i * DD * CC, t,
          ln1_w + (i + 1) * CC, ln1_b + (i + 1) * CC, ipw + (size_t)(i + 1) * CC * 2 * DD,
          xa, z, 1);
    } else {
      k_gateproj<<<BB * LL / GT, 384, 0, stream>>>(
          ysum, onw + i * DD, onb + i * DD, z, opw + (size_t)i * DD * CC, t,
          nw, nb, ipw, t2, z, 2);
    }
  }

  k_head<<<BB, 256, 0, stream>>>(t2, hw, hb, out);
}

// Round 23
// 797.939 us; speedup vs baseline: 1.0318x; 1.0164x over previous
//
#include <hip/hip_runtime.h>
#include <math.h>

#define BB 8
#define IMGS 224
#define PSZ 16
#define CC 96
#define DEPTH 12
#define NCLS 43
#define HH 14
#define WW 14
#define LL 196
#define DD 192
#define NSTATE 16
#define RRANK 6
#define KDIR 4
#define DBLC 38     // R + 2N = 6 + 32 (logical outputs of x_proj)
#define NSEG 16     // segments per chain
#define PTOK 4      // tokens per patch-embed block
// per-(b,k) dbl region: dtT[6][200] + B[196][16] + Ct[16][200]
#define TSTR 200    // row stride for dtT / Ct
#define OFF_B 1200
#define OFF_C 4336
#define DBKSZ 7552  // 1200 + 3136 + 3200 + 16 pad
#define XT 14       // tokens per x_proj tile (14 tiles -> 448 blocks)
#define XPAD 196    // x-tile row stride (mult of 4 => float4-aligned LDS reads)
#define GT 4        // tokens per gateproj block (392 blocks); 4 | 196 so same b, consecutive l
#define YSTRIDE (BB * DD * LL)  // per-direction ysum plane

__device__ __forceinline__ float wave_sum(float v) {
#pragma unroll
  for (int m = 32; m; m >>= 1) v += __shfl_xor(v, m, 64);
  return v;
}

__device__ __forceinline__ float silu_f(float x) {
  return x / (1.f + __expf(-x));
}

// ---------------- patch embed: 4 tokens/block, LDS-staged patch, contiguous weight reads ----------------
__global__ void k_patch(const float* __restrict__ x, const float* __restrict__ pw,
                        const float* __restrict__ pb, const float* __restrict__ pos,
                        float* __restrict__ t) {
  __shared__ float s_x[PTOK][768];  // 3*16*16 per token
  int tok0 = blockIdx.x * PTOK;
  for (int tk = 0; tk < PTOK; tk++) {
    int tok = tok0 + tk;
    int b = tok / LL, l = tok % LL;
    int ph = l / WW, pwc = l % WW;
    for (int e = threadIdx.x; e < 768; e += 128) {
      int ci = e >> 8, kh = (e >> 4) & 15, kw = e & 15;
      s_x[tk][e] = x[((size_t)(b * 3 + ci) * IMGS + ph * PSZ + kh) * IMGS + pwc * PSZ + kw];
    }
  }
  __syncthreads();
  if (threadIdx.x < CC) {
    int c = threadIdx.x;
    float a0 = pb[c], a1 = a0, a2 = a0, a3 = a0;
    const float* wr = pw + (size_t)c * 768;
    for (int e = 0; e < 768; e++) {
      float wv = wr[e];
      a0 += s_x[0][e] * wv;
      a1 += s_x[1][e] * wv;
      a2 += s_x[2][e] * wv;
      a3 += s_x[3][e] * wv;
    }
    float acc[4] = {a0, a1, a2, a3};
    for (int tk = 0; tk < PTOK; tk++) {
      int tok = tok0 + tk;
      t[(size_t)tok * CC + c] = acc[tk] + pos[(tok % LL) * CC + c];
    }
  }
}

// ---------------- fused LN(96) + in_proj -> xa,z (B,L,D each); layer 0 only ----------------
__global__ void k_lnproj(const float* __restrict__ t, const float* __restrict__ w,
                         const float* __restrict__ bias, const float* __restrict__ ipw,
                         float* __restrict__ xa, float* __restrict__ z) {
  __shared__ float s_x[CC];
  int tok = blockIdx.x;
  int tid = threadIdx.x;
  if (tid < 64) {
    int lane = tid;
    const float* p = t + (size_t)tok * CC;
    float v0 = p[lane];
    float v1 = (lane < CC - 64) ? p[lane + 64] : 0.f;
    float mu = wave_sum(v0 + v1) * (1.f / CC);
    float d0 = v0 - mu;
    float d1 = (lane < CC - 64) ? (v1 - mu) : 0.f;
    float var = wave_sum(d0 * d0 + d1 * d1) * (1.f / CC);
    float rs = rsqrtf(var + 1e-6f);
    s_x[lane] = d0 * rs * w[lane] + bias[lane];
    if (lane < CC - 64) s_x[lane + 64] = d1 * rs * w[lane + 64] + bias[lane + 64];
  }
  __syncthreads();
  int j = tid;  // 0..383
  float acc = 0.f;
  for (int c = 0; c < CC; c++) acc += s_x[c] * ipw[(size_t)c * (2 * DD) + j];
  if (j < DD) xa[(size_t)tok * DD + j] = acc;
  else z[(size_t)tok * DD + (j - DD)] = acc;
}

// ---------------- depthwise 3x3 + bias + SiLU -> xcT (B,L,D); float4 + interior fast path ----------------
__global__ void k_conv(const float* __restrict__ xa, const float* __restrict__ cw,
                       const float* __restrict__ cb, float* __restrict__ xcT) {
  int idx = blockIdx.x * blockDim.x + threadIdx.x;
  if (idx >= BB * LL * (DD / 4)) return;
  int d4 = idx % (DD / 4);
  int d = d4 * 4;
  int rem = idx / (DD / 4);
  int l = rem % LL;
  int b = rem / LL;
  int h = l / WW, w = l % WW;
  float a0 = cb[d], a1 = cb[d + 1], a2 = cb[d + 2], a3 = cb[d + 3];
  if (h >= 1 && h < HH - 1 && w >= 1 && w < WW - 1) {
#pragma unroll
    for (int kh = 0; kh < 3; kh++) {
#pragma unroll
      for (int kw = 0; kw < 3; kw++) {
        const float4 v = *(const float4*)(
            xa + ((size_t)(b * LL + (h + kh - 1) * WW + (w + kw - 1))) * DD + d);
        int wo = kh * 3 + kw;
        a0 += v.x * cw[(d + 0) * 9 + wo];
        a1 += v.y * cw[(d + 1) * 9 + wo];
        a2 += v.z * cw[(d + 2) * 9 + wo];
        a3 += v.w * cw[(d + 3) * 9 + wo];
      }
    }
  } else {
    for (int kh = 0; kh < 3; kh++) {
      int hh = h + kh - 1;
      if (hh < 0 || hh >= HH) continue;
      for (int kw = 0; kw < 3; kw++) {
        int ww = w + kw - 1;
        if (ww < 0 || ww >= WW) continue;
        const float4 v = *(const float4*)(xa + ((size_t)(b * LL + hh * WW + ww)) * DD + d);
        int wo = kh * 3 + kw;
        a0 += v.x * cw[(d + 0) * 9 + wo];
        a1 += v.y * cw[(d + 1) * 9 + wo];
        a2 += v.z * cw[(d + 2) * 9 + wo];
        a3 += v.w * cw[(d + 3) * 9 + wo];
      }
    }
  }
  float4 r = make_float4(silu_f(a0), silu_f(a1), silu_f(a2), silu_f(a3));
  *(float4*)(xcT + ((size_t)(b * LL) + l) * DD + d) = r;
}

// ---------------- x_proj v6: multi-c register reuse (x float4 loaded once per 3 c's) ----------------
__global__ __launch_bounds__(256, 4) void k_xproj(
    const float* __restrict__ xcT, const float* __restrict__ xpw,
    float* __restrict__ dbl) {
  __shared__ float s_w[DBLC * DD];    // 38 x 192 = 29184 B
  __shared__ float s_x[XT * XPAD];    // 14 x 196 = 10976 B
  int lt = blockIdx.x;  // 0..13
  int k = blockIdx.y;
  int b = blockIdx.z;
  int tid = threadIdx.x;
  int l0 = lt * XT;

  const float* wsrc = xpw + (size_t)k * DBLC * DD;
  for (int idx = tid; idx < DBLC * DD; idx += 256) s_w[idx] = wsrc[idx];
  for (int idx = tid; idx < XT * DD; idx += 256) {
    int i = idx / DD, d = idx % DD;
    int l = l0 + i;
    int lr = (k >= 2) ? (LL - 1 - l) : l;
    int src = (k & 1) ? ((lr % HH) * WW + lr / HH) : lr;
    s_x[i * XPAD + d] = xcT[((size_t)b * LL + src) * DD + d];
  }
  __syncthreads();

  int li = tid & 15;
  int cb = tid >> 4;        // 0..15 -> c = cb, cb+16, (cb+32 if cb<6)
  if (li >= XT) return;
  int l = l0 + li;
  float* base = dbl + (size_t)(b * KDIR + k) * DBKSZ;
  const float4* xr = (const float4*)(s_x + li * XPAD);
  const float4* w0 = (const float4*)(s_w + cb * DD);
  const float4* w1 = (const float4*)(s_w + (cb + 16) * DD);
  bool has2 = (cb < DBLC - 32);
  const float4* w2 = has2 ? (const float4*)(s_w + (cb + 32) * DD) : w0;
  float a0 = 0.f, a1 = 0.f, a2 = 0.f;
#pragma unroll 8
  for (int q = 0; q < DD / 4; q++) {
    float4 a = xr[q];
    float4 v0 = w0[q], v1 = w1[q], v2 = w2[q];
    a0 += a.x * v0.x + a.y * v0.y + a.z * v0.z + a.w * v0.w;
    a1 += a.x * v1.x + a.y * v1.y + a.z * v1.z + a.w * v1.w;
    a2 += a.x * v2.x + a.y * v2.y + a.z * v2.z + a.w * v2.w;
  }
  {
    int c = cb;
    if (c < RRANK) base[c * TSTR + l] = a0;
    else base[OFF_B + l * NSTATE + (c - RRANK)] = a0;
  }
  {
    int c = cb + 16;
    if (c < RRANK + NSTATE) base[OFF_B + l * NSTATE + (c - RRANK)] = a1;
    else base[OFF_C + (c - RRANK - NSTATE) * TSTR + l] = a1;
  }
  if (has2) {
    int c = cb + 32;
    base[OFF_C + (c - RRANK - NSTATE) * TSTR + l] = a2;
  }
}

// ---------------- selective scan v12: one block per (b, d-PAIR, k); B/C/dt-rows loaded once ----------------
__global__ __launch_bounds__(256, 4) void k_scan(
    const float* __restrict__ xcT, const float* __restrict__ dbl,
    const float* __restrict__ dtw, const float* __restrict__ dtb,
    const float* __restrict__ alog, const float* __restrict__ dsv,
    float* __restrict__ ysum) {
  __shared__ float s_h[2][NSTATE][LL + 1];  // 25.2 KB; stride 197 conflict-free
  __shared__ float s_dt[2][LL];
  __shared__ float s_u[2][LL];
  __shared__ float s_xv[2][LL];
  __shared__ float s_cumdt[2][LL];
  __shared__ unsigned short s_src[LL];
  __shared__ float s_hin[2][NSEG][NSTATE];
  __shared__ float s_hend[2][NSEG][NSTATE];
  __shared__ float s_cum[2][NSEG][NSTATE];
  __shared__ float s_segsum[2][NSEG];
  __shared__ float s_A[2][NSTATE];
  __shared__ float s_y[2][LL];
  int tid = threadIdx.x;
  int s = tid >> 4;   // segment 0..15
  int n = tid & 15;   // state
  int bd = blockIdx.x;
  int dp = bd % (DD / 2);
  int d0 = dp * 2;
  int b = bd / (DD / 2);
  int k = blockIdx.y;  // direction 0..3

  // segment extents: first 4 have 13 steps, rest 12 (4*13 + 12*12 = 196)
  int len = (s < 4) ? 13 : 12;
  int l0 = s * 12 + ((s < 4) ? s : 4);

  float A0 = -__expf(alog[((size_t)k * DD + d0) * NSTATE + n]);
  float A1 = -__expf(alog[((size_t)k * DD + d0 + 1) * NSTATE + n]);
  float Dsc0 = dsv[k * DD + d0];
  float Dsc1 = dsv[k * DD + d0 + 1];
  const float* blp = dbl + (size_t)(b * KDIR + k) * DBKSZ;
  if (tid < NSTATE) { s_A[0][tid] = A0; s_A[1][tid] = A1; }

  // ---- phase 0: parallel per-token precompute; dt-rows + xv loaded ONCE for the pair ----
  if (tid < LL) {
    int l = tid;
    float r[RRANK];
#pragma unroll
    for (int rr = 0; rr < RRANK; rr++) r[rr] = blp[rr * TSTR + l];
    const float* wp0 = dtw + ((size_t)k * DD + d0) * RRANK;
    const float* wp1 = wp0 + RRANK;
    float m0 = dtb[k * DD + d0], m1 = dtb[k * DD + d0 + 1];
#pragma unroll
    for (int rr = 0; rr < RRANK; rr++) { m0 += r[rr] * wp0[rr]; m1 += r[rr] * wp1[rr]; }
    float dt0 = (m0 > 20.f) ? m0 : __logf(1.f + __expf(m0));
    float dt1 = (m1 > 20.f) ? m1 : __logf(1.f + __expf(m1));
    int lr = (k >= 2) ? (LL - 1 - l) : l;
    int src = (k & 1) ? ((lr % HH) * WW + lr / HH) : lr;
    float2 xv = *(const float2*)(xcT + ((size_t)b * LL + src) * DD + d0);
    s_dt[0][l] = dt0; s_dt[1][l] = dt1;
    s_u[0][l] = dt0 * xv.x; s_u[1][l] = dt1 * xv.y;
    s_xv[0][l] = xv.x; s_xv[1][l] = xv.y;
    s_src[l] = (unsigned short)src;
  }
  __syncthreads();

  // per-token inclusive prefix sum of dt within its segment (both d's)
  if (tid < LL) {
    int l = tid;
    int myseg = (l < 52) ? (l / 13) : (4 + (l - 52) / 12);
    int sl0 = myseg * 12 + ((myseg < 4) ? myseg : 4);
    float a0 = 0.f, a1 = 0.f;
    for (int j = sl0; j <= l; j++) { a0 += s_dt[0][j]; a1 += s_dt[1][j]; }
    s_cumdt[0][l] = a0; s_cumdt[1][l] = a1;
    int slen = (myseg < 4) ? 13 : 12;
    if (l == sl0 + slen - 1) { s_segsum[0][myseg] = a0; s_segsum[1][myseg] = a1; }
  }
  __syncthreads();

  // ---- pass 1: two independent serial chains; B prefetched ONCE for the pair ----
  float Breg[13];
#pragma unroll
  for (int i = 0; i < 13; i++) {
    int li = (i < len) ? (l0 + i) : l0;
    Breg[i] = blp[OFF_B + li * NSTATE + n];
  }
  float h0 = 0.f, h1 = 0.f;
#pragma unroll
  for (int i = 0; i < 13; i++) {
    if (i < len) {
      int l = l0 + i;
      float a0 = __expf(s_dt[0][l] * A0);
      float a1 = __expf(s_dt[1][l] * A1);
      h0 = h0 * a0 + s_u[0][l] * Breg[i];
      h1 = h1 * a1 + s_u[1][l] * Breg[i];
      s_h[0][n][l] = h0;
      s_h[1][n][l] = h1;
    }
  }
  s_hend[0][s][n] = h0; s_hend[1][s][n] = h1;
  s_cum[0][s][n] = __expf(A0 * s_segsum[0][s]);
  s_cum[1][s][n] = __expf(A1 * s_segsum[1][s]);
  __syncthreads();

  // ---- combine: each (s,n) thread computes h_in for both d's (independent FMA chains) ----
  {
    float hh0 = 0.f, hh1 = 0.f;
    for (int ss = 0; ss < s; ss++) {
      hh0 = s_cum[0][ss][n] * hh0 + s_hend[0][ss][n];
      hh1 = s_cum[1][ss][n] * hh1 + s_hend[1][ss][n];
    }
    s_hin[0][s][n] = hh0; s_hin[1][s][n] = hh1;
  }
  __syncthreads();

  // ---- phase 2: y per token; C loaded ONCE for the pair ----
  if (tid < LL) {
    int l = tid;
    int myseg = (l < 52) ? (l / 13) : (4 + (l - 52) / 12);
    float cd0 = s_cumdt[0][l], cd1 = s_cumdt[1][l];
    const float* q = blp + OFF_C + l;  // Ct[nn][l], stride TSTR
    float y0 = 0.f, y1 = 0.f;
#pragma unroll
    for (int nn = 0; nn < NSTATE; nn++) {
      float Cv = q[nn * TSTR];
      float hf0 = s_h[0][nn][l] + __expf(s_A[0][nn] * cd0) * s_hin[0][myseg][nn];
      float hf1 = s_h[1][nn][l] + __expf(s_A[1][nn] * cd1) * s_hin[1][myseg][nn];
      y0 += hf0 * Cv;
      y1 += hf1 * Cv;
    }
    y0 += Dsc0 * s_xv[0][l];
    y1 += Dsc1 * s_xv[1][l];
    int src = s_src[l];
    s_y[0][src] = y0;
    s_y[1][src] = y1;
  }
  __syncthreads();
  if (tid < LL) {
    size_t base = (size_t)k * YSTRIDE + ((size_t)b * DD + d0) * LL;
    ysum[base + tid] = s_y[0][tid];
    ysum[base + LL + tid] = s_y[1][tid];
  }
}

// ---- fused gate+proj v5: per-wave LN(192) — stage-1 barriers 9 -> 2 ----
// wave w (0..3) owns token w: lane holds 3 elems (d, d+64, d+128); LN reduces in-wave only.
// mode 1: out_proj + residual + next-layer LN(96)+in_proj -> xa,zout
// mode 2: out_proj + residual + FINAL LN * (1/L) -> t2 (passed via xa)
__global__ void k_gateproj(const float* __restrict__ ys,
                           const float* __restrict__ onw, const float* __restrict__ onb,
                           const float* __restrict__ z, const float* __restrict__ opw,
                           float* __restrict__ t,
                           const float* __restrict__ nlw, const float* __restrict__ nlb,
                           const float* __restrict__ ipw,
                           float* __restrict__ xa, float* __restrict__ zout, int mode) {
  __shared__ float s_g[GT][DD];
  __shared__ float s_t[GT][CC];
  __shared__ float s_x[GT][CC];
  __shared__ float s_p[4][GT][CC];
  int tok0 = blockIdx.x * GT;
  int b = tok0 / LL;   // GT | LL so all 4 tokens share b
  int l0 = tok0 % LL;  // consecutive l0..l0+3
  int tid = threadIdx.x;

  // stage 1a: per-d float4 row loads (4 tokens at once), sum 4 direction planes, transpose
  if (tid < DD) {
    size_t base = ((size_t)b * DD + tid) * LL + l0;
    float4 v0 = *(const float4*)(ys + base);
    float4 v1 = *(const float4*)(ys + (size_t)YSTRIDE + base);
    float4 v2 = *(const float4*)(ys + 2 * (size_t)YSTRIDE + base);
    float4 v3 = *(const float4*)(ys + 3 * (size_t)YSTRIDE + base);
    s_g[0][tid] = v0.x + v1.x + v2.x + v3.x;
    s_g[1][tid] = v0.y + v1.y + v2.y + v3.y;
    s_g[2][tid] = v0.z + v1.z + v2.z + v3.z;
    s_g[3][tid] = v0.w + v1.w + v2.w + v3.w;
  }
  __syncthreads();

  // stage 1b: per-wave LN(192)+silu-gate; wave w = token w; no cross-wave comms
  {
    int w = tid >> 6;
    int lane = tid & 63;
    if (w < GT) {
      int tok = tok0 + w;
      float v0 = s_g[w][lane];
      float v1 = s_g[w][lane + 64];
      float v2 = s_g[w][lane + 128];
      float mu = wave_sum(v0 + v1 + v2) * (1.f / DD);
      float d0 = v0 - mu, d1 = v1 - mu, d2 = v2 - mu;
      float var = wave_sum(d0 * d0 + d1 * d1 + d2 * d2) * (1.f / DD);
      float rs = rsqrtf(var + 1e-6f);
      const float* zp = z + (size_t)tok * DD;
      s_g[w][lane]       = (d0 * rs * onw[lane] + onb[lane]) * silu_f(zp[lane]);
      s_g[w][lane + 64]  = (d1 * rs * onw[lane + 64] + onb[lane + 64]) * silu_f(zp[lane + 64]);
      s_g[w][lane + 128] = (d2 * rs * onw[lane + 128] + onb[lane + 128]) * silu_f(zp[lane + 128]);
    }
  }
  __syncthreads();

  // stage 2: out_proj partials, weights read once for 4 tokens
  {
    int c = tid % CC;
    int part = tid / CC;  // 0..3
    int dlo = part * 48;
    float a0 = 0.f, a1 = 0.f, a2 = 0.f, a3 = 0.f;
#pragma unroll 8
    for (int j = 0; j < 48; j++) {
      float wv = opw[(size_t)(dlo + j) * CC + c];
      a0 += s_g[0][dlo + j] * wv;
      a1 += s_g[1][dlo + j] * wv;
      a2 += s_g[2][dlo + j] * wv;
      a3 += s_g[3][dlo + j] * wv;
    }
    s_p[part][0][c] = a0;
    s_p[part][1][c] = a1;
    s_p[part][2][c] = a2;
    s_p[part][3][c] = a3;
  }
  __syncthreads();
  // residual + t update
  {
    int tk = tid / CC;  // 0..3
    int c = tid % CC;
    float tn = t[(size_t)(tok0 + tk) * CC + c] +
               s_p[0][tk][c] + s_p[1][tk][c] + s_p[2][tk][c] + s_p[3][tk][c];
    t[(size_t)(tok0 + tk) * CC + c] = tn;
    s_t[tk][c] = tn;
  }
  __syncthreads();

  // stage 3: LN(96) with nlw/nlb (next layer's ln1, or final norm in mode 2); per-wave
  {
    int w = tid >> 6;
    int lane = tid & 63;
    if (w < GT) {
      float v0 = s_t[w][lane];
      float v1 = (lane < CC - 64) ? s_t[w][lane + 64] : 0.f;
      float mu2 = wave_sum(v0 + v1) * (1.f / CC);
      float d0 = v0 - mu2;
      float d1 = (lane < CC - 64) ? (v1 - mu2) : 0.f;
      float var2 = wave_sum(d0 * d0 + d1 * d1) * (1.f / CC);
      float rs2 = rsqrtf(var2 + 1e-6f);
      s_x[w][lane] = d0 * rs2 * nlw[lane] + nlb[lane];
      if (lane < CC - 64) s_x[w][lane + 64] = d1 * rs2 * nlw[lane + 64] + nlb[lane + 64];
    }
  }
  __syncthreads();

  if (mode == 2) {
    int tk = tid / CC;
    int c = tid % CC;
    xa[(size_t)(tok0 + tk) * CC + c] = s_x[tk][c] * (1.f / LL);
    return;
  }

  // stage 4: next layer's in_proj, weights read once for 4 tokens
  {
    float b0 = 0.f, b1 = 0.f, b2 = 0.f, b3 = 0.f;
    for (int c = 0; c < CC; c++) {
      float wv = ipw[(size_t)c * (2 * DD) + tid];
      b0 += s_x[0][c] * wv;
      b1 += s_x[1][c] * wv;
      b2 += s_x[2][c] * wv;
      b3 += s_x[3][c] * wv;
    }
    float acc[GT] = {b0, b1, b2, b3};
#pragma unroll
    for (int tk = 0; tk < GT; tk++) {
      int tok = tok0 + tk;
      if (tid < DD) xa[(size_t)tok * DD + tid] = acc[tk];
      else zout[(size_t)tok * DD + (tid - DD)] = acc[tk];
    }
  }
}

// ---------------- pooled head: 8 blocks x 256 thr; 2-way parallel pool + 96x43 matmul ----------------
__global__ void k_head(const float* __restrict__ t2, const float* __restrict__ hw,
                       const float* __restrict__ hb, float* __restrict__ out) {
  __shared__ float s_part[2][CC];
  __shared__ float s_pool[CC];
  int b = blockIdx.x;
  int tid = threadIdx.x;
  if (tid < 2 * CC) {
    int part = tid / CC;
    int c = tid % CC;
    int l0 = part * 98;
    float acc = 0.f;
    for (int i = 0; i < 98; i++) acc += t2[((size_t)b * LL + l0 + i) * CC + c];
    s_part[part][c] = acc;
  }
  __syncthreads();
  if (tid < CC) s_pool[tid] = s_part[0][tid] + s_part[1][tid];
  __syncthreads();
  if (tid < NCLS) {
    float acc = hb[tid];
    for (int c = 0; c < CC; c++) acc += s_pool[c] * hw[c * NCLS + tid];
    out[b * NCLS + tid] = acc;
  }
}

extern "C" void kernel_launch(void* const* d_in, const int* in_sizes, int n_in,
                              void* d_out, int out_size, void* d_ws, size_t ws_size,
                              hipStream_t stream) {
  const float* x       = (const float*)d_in[0];
  const float* patch_w = (const float*)d_in[1];
  const float* patch_b = (const float*)d_in[2];
  const float* pos     = (const float*)d_in[3];
  const float* ln1_w   = (const float*)d_in[4];
  const float* ln1_b   = (const float*)d_in[5];
  const float* ipw     = (const float*)d_in[6];
  const float* cw      = (const float*)d_in[7];
  const float* cb      = (const float*)d_in[8];
  const float* xpw     = (const float*)d_in[9];
  const float* dtw     = (const float*)d_in[10];
  const float* dtb     = (const float*)d_in[11];
  const float* alog    = (const float*)d_in[12];
  const float* dsp     = (const float*)d_in[13];
  const float* onw     = (const float*)d_in[14];
  const float* onb     = (const float*)d_in[15];
  const float* opw     = (const float*)d_in[16];
  const float* nw      = (const float*)d_in[17];
  const float* nb      = (const float*)d_in[18];
  const float* hw      = (const float*)d_in[19];
  const float* hb      = (const float*)d_in[20];
  float* out = (float*)d_out;

  // Workspace (all separate; ws_size = 256 MiB):
  // t + xa + z + xcT + dbl + ysum(4 planes) + t2 = ~10 MB
  float* wsf  = (float*)d_ws;
  float* t    = wsf;
  float* xa   = t    + BB * LL * CC;
  float* z    = xa   + BB * LL * DD;
  float* xcT  = z    + BB * LL * DD;
  float* dbl  = xcT  + BB * LL * DD;
  float* ysum = dbl  + BB * KDIR * DBKSZ;
  float* t2   = ysum + (size_t)KDIR * YSTRIDE;

  k_patch<<<BB * LL / PTOK, 128, 0, stream>>>(x, patch_w, patch_b, pos, t);
  k_lnproj<<<BB * LL, 384, 0, stream>>>(t, ln1_w, ln1_b, ipw, xa, z);

  for (int i = 0; i < DEPTH; i++) {
    k_conv<<<(BB * LL * (DD / 4) + 255) / 256, 256, 0, stream>>>(
        xa, cw + i * DD * 9, cb + i * DD, xcT);
    k_xproj<<<dim3(LL / XT, KDIR, BB), 256, 0, stream>>>(
        xcT, xpw + (size_t)i * KDIR * DBLC * DD, dbl);
    // one block per (b, d-pair, k): 768 x 4 blocks
    k_scan<<<dim3(BB * DD / 2, KDIR), 256, 0, stream>>>(
        xcT, dbl, dtw + (size_t)i * KDIR * DD * RRANK, dtb + i * KDIR * DD,
        alog + (size_t)i * KDIR * DD * NSTATE, dsp + i * KDIR * DD, ysum);
    if (i < DEPTH - 1) {
      k_gateproj<<<BB * LL / GT, 384, 0, stream>>>(
          ysum, onw + i * DD, onb + i * DD, z, opw + (size_t)i * DD * CC, t,
          ln1_w + (i + 1) * CC, ln1_b + (i + 1) * CC, ipw + (size_t)(i + 1) * CC * 2 * DD,
          xa, z, 1);
    } else {
      k_gateproj<<<BB * LL / GT, 384, 0, stream>>>(
          ysum, onw + i * DD, onb + i * DD, z, opw + (size_t)i * DD * CC, t,
          nw, nb, ipw, t2, z, 2);
    }
  }

  k_head<<<BB, 256, 0, stream>>>(t2, hw, hb, out);
}